// Round 19
// baseline (334.439 us; speedup 1.0000x reference)
//
#include <hip/hip_runtime.h>
#include <hip/hip_bf16.h>

// GIN forward, MI355X. R19 = R18 + agg2 half-split (final diagnostic to surface
// GEMM counters now that k_pre's hist mask is fixed). All else identical.

#define NN 50000
#define EE 800000
#define FDIM 128
#define HDIM 256
#define CDIM 40
#define BN_EPS 1e-5f

typedef unsigned short u16;
typedef unsigned int u32;
typedef __attribute__((ext_vector_type(8))) short short8;
typedef __attribute__((ext_vector_type(4))) float f32x4;

__device__ __forceinline__ float bflo(u32 u) { return __uint_as_float(u << 16); }
__device__ __forceinline__ float bfhi(u32 u) { return __uint_as_float(u & 0xFFFF0000u); }
__device__ __forceinline__ u16 f2bf(float f) {
  __hip_bfloat16 h = __float2bfloat16(f);
  return *(u16*)&h;
}
__device__ __forceinline__ u32 pack2(float a, float b) {
  return (u32)f2bf(a) | ((u32)f2bf(b) << 16);
}

// ---------------- CSR build ----------------
__global__ void k_scan_blocks(const int* __restrict__ in, int* __restrict__ partial,
                              int* __restrict__ bsums, int n) {
  __shared__ int s[256];
  int i = blockIdx.x * 256 + threadIdx.x;
  s[threadIdx.x] = (i < n) ? in[i] : 0;
  __syncthreads();
  for (int d = 1; d < 256; d <<= 1) {
    int t = (threadIdx.x >= d) ? s[threadIdx.x - d] : 0;
    __syncthreads();
    s[threadIdx.x] += t;
    __syncthreads();
  }
  if (i < n) partial[i] = s[threadIdx.x];
  if (threadIdx.x == 255) bsums[blockIdx.x] = s[255];
}

__global__ void k_scan_sums(int* __restrict__ bs, int nb) {
  __shared__ int s[256];
  s[threadIdx.x] = (threadIdx.x < nb) ? bs[threadIdx.x] : 0;
  __syncthreads();
  for (int d = 1; d < 256; d <<= 1) {
    int t = (threadIdx.x >= d) ? s[threadIdx.x - d] : 0;
    __syncthreads();
    s[threadIdx.x] += t;
    __syncthreads();
  }
  int ex = (threadIdx.x == 0) ? 0 : s[threadIdx.x - 1];
  if (threadIdx.x < nb) bs[threadIdx.x] = ex;
}

__global__ void k_scan_add(const int* __restrict__ partial, const int* __restrict__ bs,
                           const int* __restrict__ deg,
                           int* __restrict__ rowstart, int* __restrict__ cursor, int n) {
  int i = blockIdx.x * 256 + threadIdx.x;
  if (i < n) {
    int incl = partial[i] + bs[blockIdx.x];
    rowstart[i + 1] = incl;
    cursor[i] = incl - deg[i];
  }
  if (i == 0) rowstart[0] = 0;
}

// XCD-spatial scatter (window = bid&7): proven -9us in R16.
#define SC_CHUNK 1024
#define SC_NCHUNK ((EE + SC_CHUNK - 1) / SC_CHUNK)   // 782
#define SC_NWIN 8
#define SC_WINSZ 6250
__global__ __launch_bounds__(256)
void k_scatter(const int* __restrict__ ei, int* __restrict__ cursor,
               int* __restrict__ sorted_src) {
  int win = blockIdx.x & (SC_NWIN - 1);
  int chunk = blockIdx.x >> 3;
  int wlo = win * SC_WINSZ, whi = wlo + SC_WINSZ;
  int e0 = chunk * SC_CHUNK + threadIdx.x * 4;
  if (e0 >= EE) return;
  int4 s4 = *(const int4*)&ei[e0];
  int4 d4 = *(const int4*)&ei[EE + e0];
  int ss[4] = {s4.x, s4.y, s4.z, s4.w};
  int dd[4] = {d4.x, d4.y, d4.z, d4.w};
#pragma unroll
  for (int i = 0; i < 4; ++i) {
    if (dd[i] >= wlo && dd[i] < whi) {
      int p = atomicAdd(&cursor[dd[i]], 1);
      sorted_src[p] = ss[i];
    }
  }
}

// ---------------- fused prework: cvt_x | cvt_w | XCD-windowed hist ----------------
#define NB_CVTX 6250
#define NB_CVTW 944
#define HI_CHUNK 1024
#define HI_NCHUNK ((EE + HI_CHUNK - 1) / HI_CHUNK)   // 782
#define NB_HIST (HI_NCHUNK * 8)
__global__ void k_pre(const float* __restrict__ x, u16* __restrict__ xb,
                      const int* __restrict__ ei, int* __restrict__ deg,
                      const float* __restrict__ W1, const float* __restrict__ W2,
                      const float* __restrict__ W3, const float* __restrict__ W4,
                      const float* __restrict__ Wf,
                      u16* __restrict__ W1t, u16* __restrict__ W2t,
                      u16* __restrict__ W3t, u16* __restrict__ W4t,
                      u16* __restrict__ Wft) {
  int b = blockIdx.x, t = threadIdx.x;
  if (b < NB_CVTX) {
    size_t base = ((size_t)b * 256 + t) * 4;
    float4 v = *(const float4*)&x[base];
    *(uint2*)&xb[base] = make_uint2(pack2(v.x, v.y), pack2(v.z, v.w));
  } else if (b < NB_CVTX + NB_CVTW) {
    int bb = b - NB_CVTX;
    if (bb < 128) {
      int i = bb * 256 + t; int k = i >> 8, n = i & 255;
      W1t[(size_t)n * 128 + (((k >> 3) ^ (n & 7)) << 3) + (k & 7)] = f2bf(W1[i]);
    } else if (bb < 384) {
      int i = (bb - 128) * 256 + t; int k = i >> 8, n = i & 255;
      W2t[(size_t)n * 256 + (((k >> 3) ^ (n & 7)) << 3) + (k & 7)] = f2bf(W2[i]);
    } else if (bb < 640) {
      int i = (bb - 384) * 256 + t; int k = i >> 8, n = i & 255;
      W3t[(size_t)n * 256 + (((k >> 3) ^ (n & 7)) << 3) + (k & 7)] = f2bf(W3[i]);
    } else if (bb < 896) {
      int i = (bb - 640) * 256 + t; int k = i >> 8, n = i & 255;
      W4t[(size_t)n * 256 + (((k >> 3) ^ (n & 7)) << 3) + (k & 7)] = f2bf(W4[i]);
    } else {
      int j = (bb - 896) * 256 + t;
      int c = j >> 8, k = j & 255;
      float v = (c < CDIM) ? Wf[(size_t)k * CDIM + c] : 0.f;
      Wft[(size_t)c * 256 + (((k >> 3) ^ (c & 7)) << 3) + (k & 7)] = f2bf(v);
    }
  } else {
    int hb = b - NB_CVTX - NB_CVTW;
    int win = blockIdx.x & 7;
    int chunk = hb >> 3;
    int wlo = win * SC_WINSZ, whi = wlo + SC_WINSZ;
    int e0 = chunk * HI_CHUNK + t * 4;
    if (e0 >= EE) return;
    int4 d4 = *(const int4*)&ei[EE + e0];
    int dd[4] = {d4.x, d4.y, d4.z, d4.w};
#pragma unroll
    for (int i = 0; i < 4; ++i) {
      if (dd[i] >= wlo && dd[i] < whi) atomicAdd(&deg[dd[i]], 1);
    }
  }
}

// ---------------- aggregation (node range) ----------------
template <int FEAT>
__global__ __launch_bounds__(256)
void k_agg(const u16* __restrict__ x, const int* __restrict__ rowstart,
           const int* __restrict__ sorted_src, const float* __restrict__ epsp,
           u16* __restrict__ out, int node0, int node1) {
  int node = node0 + blockIdx.x * 4 + (threadIdx.x >> 6);
  if (node >= node1) return;
  int lane = threadIdx.x & 63;
  float e1 = 1.0f + epsp[0];
  int s = rowstart[node], t = rowstart[node + 1];
  if constexpr (FEAT == 128) {
    const u32* xp = (const u32*)x;
    u32 u = xp[(size_t)node * 64 + lane];
    float a0 = bflo(u) * e1, a1 = bfhi(u) * e1;
    int p = s;
    for (; p + 7 < t; p += 8) {
      u32 uu[8];
#pragma unroll
      for (int i = 0; i < 8; ++i) uu[i] = xp[(size_t)sorted_src[p + i] * 64 + lane];
#pragma unroll
      for (int i = 0; i < 8; ++i) { a0 += bflo(uu[i]); a1 += bfhi(uu[i]); }
    }
    for (; p < t; ++p) {
      u32 u0 = xp[(size_t)sorted_src[p] * 64 + lane];
      a0 += bflo(u0); a1 += bfhi(u0);
    }
    ((u32*)out)[(size_t)node * 64 + lane] = pack2(a0, a1);
  } else {
    const uint2* xp = (const uint2*)x;
    uint2 u = xp[(size_t)node * 64 + lane];
    float a0 = bflo(u.x) * e1, a1 = bfhi(u.x) * e1;
    float a2 = bflo(u.y) * e1, a3 = bfhi(u.y) * e1;
    int p = s;
    for (; p + 7 < t; p += 8) {
      uint2 uu[8];
#pragma unroll
      for (int i = 0; i < 8; ++i) uu[i] = xp[(size_t)sorted_src[p + i] * 64 + lane];
#pragma unroll
      for (int i = 0; i < 8; ++i) {
        a0 += bflo(uu[i].x); a1 += bfhi(uu[i].x);
        a2 += bflo(uu[i].y); a3 += bfhi(uu[i].y);
      }
    }
    for (; p < t; ++p) {
      uint2 u0 = xp[(size_t)sorted_src[p] * 64 + lane];
      a0 += bflo(u0.x); a1 += bfhi(u0.x);
      a2 += bflo(u0.y); a3 += bfhi(u0.y);
    }
    ((uint2*)out)[(size_t)node * 64 + lane] = make_uint2(pack2(a0, a1), pack2(a2, a3));
  }
}

// ---------------- 128x256-tile MFMA GEMM with T14 A-prefetch (unchanged) ----------------
template <int K, bool TRANSFORM, bool RELU_OUT, bool COLSUMS>
__global__ __launch_bounds__(512, 4)
void k_gemm(const u16* __restrict__ A, const u16* __restrict__ Wt,
            const float* __restrict__ bias,
            const float* __restrict__ icsum, const float* __restrict__ icsq,
            const float* __restrict__ g, const float* __restrict__ be,
            u16* __restrict__ C, float* __restrict__ ocsum, float* __restrict__ ocsq) {
  __shared__ u16 SMEM[128 * 64 + 256 * 64];
  __shared__ float2 Tb[TRANSFORM ? 256 : 1];
  u16* Asm = SMEM;
  u16* Bsm = SMEM + 128 * 64;

  const int tid = threadIdx.x;
  const int lane = tid & 63;
  const int w = tid >> 6;
  const int wm = w >> 2, wn = w & 3;
  const int lr = lane & 15, lq = lane >> 4;
  const int r0 = blockIdx.x * 128;

  if constexpr (TRANSFORM) {
    if (tid < 256) {
      float m = icsum[tid] * (1.0f / NN);
      float var = icsq[tid] * (1.0f / NN) - m * m;
      float s = g[tid] * rsqrtf(var + BN_EPS);
      Tb[tid] = make_float2(s, be[tid] - m * s);
    }
    __syncthreads();
  }

  f32x4 acc[4][4];
#pragma unroll
  for (int mi = 0; mi < 4; ++mi)
#pragma unroll
    for (int ni = 0; ni < 4; ++ni) acc[mi][ni] = (f32x4){0.f, 0.f, 0.f, 0.f};

  const int srow = tid >> 3;
  const int sc = tid & 7;

  short8 pa[2];
  auto LOADA = [&](int k0) {
#pragma unroll
    for (int it = 0; it < 2; ++it) {
      int gr = r0 + it * 64 + srow;
      int grc = gr < NN ? gr : NN - 1;
      pa[it] = *(const short8*)&A[(size_t)grc * K + k0 + sc * 8];
    }
  };

  LOADA(0);
  for (int k0 = 0; k0 < K; k0 += 64) {
    if (k0 > 0) __syncthreads();
#pragma unroll
    for (int it = 0; it < 2; ++it) {
      int row = it * 64 + srow;
      short8 va = pa[it];
      if constexpr (TRANSFORM) {
#pragma unroll
        for (int j = 0; j < 8; ++j) {
          float2 tb = Tb[k0 + sc * 8 + j];
          float f = fmaxf(fmaf(__uint_as_float(((u32)(u16)va[j]) << 16), tb.x, tb.y), 0.f);
          va[j] = (short)f2bf(f);
        }
      }
      ((short8*)Asm)[row * 8 + (sc ^ (row & 7))] = va;
    }
#pragma unroll
    for (int it = 0; it < 4; ++it) {
      int row = it * 64 + srow;
      short8 vb = *(const short8*)&Wt[(size_t)row * K + k0 + sc * 8];
      ((short8*)Bsm)[row * 8 + sc] = vb;
    }
    if (k0 + 64 < K) LOADA(k0 + 64);
    __syncthreads();

#pragma unroll
    for (int ks = 0; ks < 2; ++ks) {
      short8 af[4], bfx[4];
#pragma unroll
      for (int mi = 0; mi < 4; ++mi) {
        int row = wm * 64 + mi * 16 + lr;
        af[mi] = ((const short8*)Asm)[row * 8 + ((ks * 4 + lq) ^ (row & 7))];
      }
#pragma unroll
      for (int ni = 0; ni < 4; ++ni) {
        int rn = wn * 64 + ni * 16 + lr;
        bfx[ni] = ((const short8*)Bsm)[rn * 8 + ((ks * 4 + lq) ^ (rn & 7))];
      }
#pragma unroll
      for (int mi = 0; mi < 4; ++mi)
#pragma unroll
        for (int ni = 0; ni < 4; ++ni)
          acc[mi][ni] = __builtin_amdgcn_mfma_f32_16x16x32_bf16(af[mi], bfx[ni], acc[mi][ni], 0, 0, 0);
    }
  }
  __syncthreads();

  float bv[4];
#pragma unroll
  for (int ni = 0; ni < 4; ++ni) bv[ni] = bias[wn * 64 + ni * 16 + lr];
  float colS[4] = {}, colQ[4] = {};

  u16* Cs = SMEM;
#pragma unroll
  for (int r = 0; r < 2; ++r) {
    if (wm == r) {
#pragma unroll
      for (int mi = 0; mi < 4; ++mi)
#pragma unroll
        for (int ni = 0; ni < 4; ++ni) {
          int col = wn * 64 + ni * 16 + lr;
#pragma unroll
          for (int j = 0; j < 4; ++j) {
            int lrow = mi * 16 + lq * 4 + j;
            float v = acc[mi][ni][j] + bv[ni];
            if constexpr (RELU_OUT) v = fmaxf(v, 0.f);
            if constexpr (COLSUMS) {
              if (r0 + r * 64 + lrow < NN) { colS[ni] += v; colQ[ni] += v * v; }
            }
            Cs[lrow * 256 + col] = f2bf(v);
          }
        }
    }
    __syncthreads();
    {
      int lrow = tid >> 3;
      int gr = r0 + r * 64 + lrow;
      if (gr < NN) {
        int co = (tid & 7) * 32;
#pragma unroll
        for (int i = 0; i < 4; ++i)
          *(uint4*)&C[(size_t)gr * 256 + co + i * 8] = *(const uint4*)&Cs[lrow * 256 + co + i * 8];
      }
    }
    __syncthreads();
  }

  if constexpr (COLSUMS) {
#pragma unroll
    for (int ni = 0; ni < 4; ++ni) {
      float s = colS[ni], q = colQ[ni];
      s += __shfl_xor(s, 16); s += __shfl_xor(s, 32);
      q += __shfl_xor(q, 16); q += __shfl_xor(q, 32);
      if (lq == 0) {
        int col = wn * 64 + ni * 16 + lr;
        atomicAdd(&ocsum[col], s);
        atomicAdd(&ocsq[col], q);
      }
    }
  }
}

// ---------------- final: out[N,40] = relu(bn3(z3)) @ Wf + bf ----------------
__global__ __launch_bounds__(512)
void k_final(const u16* __restrict__ z3, const u16* __restrict__ Wft,
             const float* __restrict__ bfp,
             const float* __restrict__ icsum, const float* __restrict__ icsq,
             const float* __restrict__ g, const float* __restrict__ be,
             float* __restrict__ out) {
  __shared__ u16 Bs[48 * 256];
  __shared__ float2 Tb[256];
  const int tid = threadIdx.x;
  const int lane = tid & 63;
  const int w = tid >> 6;
  const int lr = lane & 15, lq = lane >> 4;
  const int r0 = blockIdx.x * 128;

  int row = r0 + w * 16 + lr;
  int rc = row < NN ? row : NN - 1;
  const u16* Ap = &z3[(size_t)rc * 256];
  short8 a[8];
#pragma unroll
  for (int ks = 0; ks < 8; ++ks)
    a[ks] = *(const short8*)&Ap[(ks * 4 + lq) * 8];

  {
    const short8* Bv = (const short8*)Wft;
    short8* Bl = (short8*)Bs;
#pragma unroll
    for (int i = 0; i < 3; ++i)
      Bl[tid + i * 512] = Bv[tid + i * 512];
  }
  if (tid < 256) {
    float m = icsum[tid] * (1.0f / NN);
    float var = icsq[tid] * (1.0f / NN) - m * m;
    float s = g[tid] * rsqrtf(var + BN_EPS);
    Tb[tid] = make_float2(s, be[tid] - m * s);
  }
  __syncthreads();

  f32x4 acc[3];
#pragma unroll
  for (int ni = 0; ni < 3; ++ni) acc[ni] = (f32x4){0.f, 0.f, 0.f, 0.f};
#pragma unroll
  for (int ks = 0; ks < 8; ++ks) {
    short8 t0 = a[ks];
    int kb = (ks * 4 + lq) * 8;
#pragma unroll
    for (int j = 0; j < 8; ++j) {
      float2 tb = Tb[kb + j];
      float f0 = fmaxf(fmaf(__uint_as_float(((u32)(u16)t0[j]) << 16), tb.x, tb.y), 0.f);
      t0[j] = (short)f2bf(f0);
    }
#pragma unroll
    for (int ni = 0; ni < 3; ++ni) {
      int col = ni * 16 + lr;
      short8 bfr = *(const short8*)&Bs[(size_t)col * 256 + (((ks * 4 + lq) ^ (col & 7)) << 3)];
      acc[ni] = __builtin_amdgcn_mfma_f32_16x16x32_bf16(t0, bfr, acc[ni], 0, 0, 0);
    }
  }

#pragma unroll
  for (int ni = 0; ni < 3; ++ni) {
    int col = ni * 16 + lr;
    if (col < CDIM) {
      float bfv = bfp[col];
#pragma unroll
      for (int j = 0; j < 4; ++j) {
        int gr = r0 + w * 16 + lq * 4 + j;
        if (gr < NN) out[(size_t)gr * CDIM + col] = acc[ni][j] + bfv;
      }
    }
  }
}

// ---------------- launch ----------------
extern "C" void kernel_launch(void* const* d_in, const int* in_sizes, int n_in,
                              void* d_out, int out_size, void* d_ws, size_t ws_size,
                              hipStream_t stream) {
  const float* x   = (const float*)d_in[0];
  const int*   ei  = (const int*)d_in[1];
  const float* eps1= (const float*)d_in[2];
  const float* W1  = (const float*)d_in[3];
  const float* b1  = (const float*)d_in[4];
  const float* g1  = (const float*)d_in[5];
  const float* be1 = (const float*)d_in[6];
  const float* W2  = (const float*)d_in[7];
  const float* b2  = (const float*)d_in[8];
  const float* eps2= (const float*)d_in[9];
  const float* W3  = (const float*)d_in[10];
  const float* b3  = (const float*)d_in[11];
  const float* g2  = (const float*)d_in[12];
  const float* be2 = (const float*)d_in[13];
  const float* W4  = (const float*)d_in[14];
  const float* b4  = (const float*)d_in[15];
  const float* g3  = (const float*)d_in[16];
  const float* be3 = (const float*)d_in[17];
  const float* Wf  = (const float*)d_in[18];
  const float* bf  = (const float*)d_in[19];
  float* out = (float*)d_out;

  char* p = (char*)d_ws;
  auto alloc = [&](size_t bytes) -> char* {
    char* r = p;
    p += (bytes + 255) & ~(size_t)255;
    return r;
  };
  float* stats   = (float*)alloc(6 * 256 * sizeof(float));
  int* deg       = (int*)alloc(NN * sizeof(int));
  int* rowstart  = (int*)alloc((NN + 16) * sizeof(int));
  int* cursor    = (int*)alloc(NN * sizeof(int));
  int* sorted    = (int*)alloc(EE * sizeof(int));
  int* partial   = (int*)alloc(NN * sizeof(int));
  int* bsums     = (int*)alloc(1024 * sizeof(int));
  u16* W1t       = (u16*)alloc(256 * 128 * sizeof(u16));
  u16* W2t       = (u16*)alloc(256 * 256 * sizeof(u16));
  u16* W3t       = (u16*)alloc(256 * 256 * sizeof(u16));
  u16* W4t       = (u16*)alloc(256 * 256 * sizeof(u16));
  u16* Wft       = (u16*)alloc(48 * 256 * sizeof(u16));
  u16* xb        = (u16*)alloc((size_t)NN * 128 * sizeof(u16));
  u16* A1        = (u16*)alloc((size_t)NN * 128 * sizeof(u16));
  u16* z1        = (u16*)alloc((size_t)NN * 256 * sizeof(u16));
  u16* h1        = (u16*)alloc((size_t)NN * 256 * sizeof(u16));
  u16* A2        = (u16*)alloc((size_t)NN * 256 * sizeof(u16));
  (void)alloc(64 * 1024);  // guard pad
  u16* z2 = z1;
  u16* z3 = h1;

  float* s1 = stats + 0,    *q1 = stats + 256;
  float* s2 = stats + 512,  *q2 = stats + 768;
  float* s3 = stats + 1024, *q3 = stats + 1280;

  const int nbN = (NN + 255) / 256;

  hipMemsetAsync(stats, 0, 6 * 256 * sizeof(float) + NN * sizeof(int), stream);

  k_pre<<<NB_CVTX + NB_CVTW + NB_HIST, 256, 0, stream>>>(
      x, xb, ei, deg, W1, W2, W3, W4, Wf, W1t, W2t, W3t, W4t, Wft);
  k_scan_blocks<<<nbN, 256, 0, stream>>>(deg, partial, bsums, NN);
  k_scan_sums<<<1, 256, 0, stream>>>(bsums, nbN);
  k_scan_add<<<nbN, 256, 0, stream>>>(partial, bsums, deg, rowstart, cursor, NN);
  k_scatter<<<SC_NCHUNK * SC_NWIN, 256, 0, stream>>>(ei, cursor, sorted);

  const int gGemm = (NN + 127) / 128;   // 391
  const int NH = 25000;
  const int gAggH = (NH + 3) / 4;       // 6250

  // conv1
  k_agg<128><<<(NN + 3) / 4, 256, 0, stream>>>(xb, rowstart, sorted, eps1, A1, 0, NN);
  k_gemm<128, false, false, true><<<gGemm, 512, 0, stream>>>(
      A1, W1t, b1, nullptr, nullptr, nullptr, nullptr, z1, s1, q1);
  k_gemm<256, true, true, false><<<gGemm, 512, 0, stream>>>(
      z1, W2t, b2, s1, q1, g1, be1, h1, nullptr, nullptr);

  // conv2 (agg2 split: GEMMs become the slowest class -> counters surface)
  k_agg<256><<<gAggH, 256, 0, stream>>>(h1, rowstart, sorted, eps2, A2, 0, NH);
  k_agg<256><<<gAggH, 256, 0, stream>>>(h1, rowstart, sorted, eps2, A2, NH, NN);
  k_gemm<256, false, false, true><<<gGemm, 512, 0, stream>>>(
      A2, W3t, b3, nullptr, nullptr, nullptr, nullptr, z2, s2, q2);
  k_gemm<256, true, false, true><<<gGemm, 512, 0, stream>>>(
      z2, W4t, b4, s2, q2, g2, be2, z3, s3, q3);

  // final
  k_final<<<(NN + 127) / 128, 512, 0, stream>>>(z3, Wft, bf, s3, q3, g3, be3, out);
}

// Round 20
// 324.265 us; speedup vs baseline: 1.0314x; 1.0314x over previous
//
#include <hip/hip_runtime.h>
#include <hip/hip_bf16.h>

// GIN forward, MI355X. R20 = R16 base + BK=32 double-buffered 2-phase GEMM
// (issue loads -> MFMA -> write-next -> 1 barrier/step), plain-transposed weights.

#define NN 50000
#define EE 800000
#define FDIM 128
#define HDIM 256
#define CDIM 40
#define BN_EPS 1e-5f

typedef unsigned short u16;
typedef unsigned int u32;
typedef __attribute__((ext_vector_type(8))) short short8;
typedef __attribute__((ext_vector_type(4))) float f32x4;

__device__ __forceinline__ float bflo(u32 u) { return __uint_as_float(u << 16); }
__device__ __forceinline__ float bfhi(u32 u) { return __uint_as_float(u & 0xFFFF0000u); }
__device__ __forceinline__ u16 f2bf(float f) {
  __hip_bfloat16 h = __float2bfloat16(f);
  return *(u16*)&h;
}
__device__ __forceinline__ u32 pack2(float a, float b) {
  return (u32)f2bf(a) | ((u32)f2bf(b) << 16);
}

// ---------------- CSR build ----------------
__global__ void k_scan_blocks(const int* __restrict__ in, int* __restrict__ partial,
                              int* __restrict__ bsums, int n) {
  __shared__ int s[256];
  int i = blockIdx.x * 256 + threadIdx.x;
  s[threadIdx.x] = (i < n) ? in[i] : 0;
  __syncthreads();
  for (int d = 1; d < 256; d <<= 1) {
    int t = (threadIdx.x >= d) ? s[threadIdx.x - d] : 0;
    __syncthreads();
    s[threadIdx.x] += t;
    __syncthreads();
  }
  if (i < n) partial[i] = s[threadIdx.x];
  if (threadIdx.x == 255) bsums[blockIdx.x] = s[255];
}

__global__ void k_scan_sums(int* __restrict__ bs, int nb) {
  __shared__ int s[256];
  s[threadIdx.x] = (threadIdx.x < nb) ? bs[threadIdx.x] : 0;
  __syncthreads();
  for (int d = 1; d < 256; d <<= 1) {
    int t = (threadIdx.x >= d) ? s[threadIdx.x - d] : 0;
    __syncthreads();
    s[threadIdx.x] += t;
    __syncthreads();
  }
  int ex = (threadIdx.x == 0) ? 0 : s[threadIdx.x - 1];
  if (threadIdx.x < nb) bs[threadIdx.x] = ex;
}

__global__ void k_scan_add(const int* __restrict__ partial, const int* __restrict__ bs,
                           const int* __restrict__ deg,
                           int* __restrict__ rowstart, int* __restrict__ cursor, int n) {
  int i = blockIdx.x * 256 + threadIdx.x;
  if (i < n) {
    int incl = partial[i] + bs[blockIdx.x];
    rowstart[i + 1] = incl;
    cursor[i] = incl - deg[i];
  }
  if (i == 0) rowstart[0] = 0;
}

// XCD-spatial scatter (window = bid&7): proven -9us in R16 (plain-store locality).
#define SC_CHUNK 1024
#define SC_NCHUNK ((EE + SC_CHUNK - 1) / SC_CHUNK)   // 782
#define SC_NWIN 8
#define SC_WINSZ 6250
__global__ __launch_bounds__(256)
void k_scatter(const int* __restrict__ ei, int* __restrict__ cursor,
               int* __restrict__ sorted_src) {
  int win = blockIdx.x & (SC_NWIN - 1);
  int chunk = blockIdx.x >> 3;
  int wlo = win * SC_WINSZ, whi = wlo + SC_WINSZ;
  int e0 = chunk * SC_CHUNK + threadIdx.x * 4;
  if (e0 >= EE) return;
  int4 s4 = *(const int4*)&ei[e0];
  int4 d4 = *(const int4*)&ei[EE + e0];
  int ss[4] = {s4.x, s4.y, s4.z, s4.w};
  int dd[4] = {d4.x, d4.y, d4.z, d4.w};
#pragma unroll
  for (int i = 0; i < 4; ++i) {
    if (dd[i] >= wlo && dd[i] < whi) {
      int p = atomicAdd(&cursor[dd[i]], 1);
      sorted_src[p] = ss[i];
    }
  }
}

// ---------------- fused prework: cvt_x | cvt_w (plain transpose) | hist ----------------
#define NB_CVTX 6250
#define NB_CVTW 944
#define NB_HIST 3125
__global__ void k_pre(const float* __restrict__ x, u16* __restrict__ xb,
                      const int* __restrict__ ei, int* __restrict__ deg,
                      const float* __restrict__ W1, const float* __restrict__ W2,
                      const float* __restrict__ W3, const float* __restrict__ W4,
                      const float* __restrict__ Wf,
                      u16* __restrict__ W1t, u16* __restrict__ W2t,
                      u16* __restrict__ W3t, u16* __restrict__ W4t,
                      u16* __restrict__ Wft) {
  int b = blockIdx.x, t = threadIdx.x;
  if (b < NB_CVTX) {
    size_t base = ((size_t)b * 256 + t) * 4;
    float4 v = *(const float4*)&x[base];
    *(uint2*)&xb[base] = make_uint2(pack2(v.x, v.y), pack2(v.z, v.w));
  } else if (b < NB_CVTX + NB_CVTW) {
    int bb = b - NB_CVTX;
    if (bb < 128) {
      int i = bb * 256 + t; int k = i >> 8, n = i & 255;
      W1t[(size_t)n * 128 + k] = f2bf(W1[i]);
    } else if (bb < 384) {
      int i = (bb - 128) * 256 + t; int k = i >> 8, n = i & 255;
      W2t[(size_t)n * 256 + k] = f2bf(W2[i]);
    } else if (bb < 640) {
      int i = (bb - 384) * 256 + t; int k = i >> 8, n = i & 255;
      W3t[(size_t)n * 256 + k] = f2bf(W3[i]);
    } else if (bb < 896) {
      int i = (bb - 640) * 256 + t; int k = i >> 8, n = i & 255;
      W4t[(size_t)n * 256 + k] = f2bf(W4[i]);
    } else {
      // Wft keeps the 8-chunk swizzle (k_final consumes it)
      int j = (bb - 896) * 256 + t;
      int c = j >> 8, k = j & 255;
      float v = (c < CDIM) ? Wf[(size_t)k * CDIM + c] : 0.f;
      Wft[(size_t)c * 256 + (((k >> 3) ^ (c & 7)) << 3) + (k & 7)] = f2bf(v);
    }
  } else {
    int e = (b - NB_CVTX - NB_CVTW) * 256 + t;
    atomicAdd(&deg[ei[EE + e]], 1);
  }
}

// ---------------- aggregation (bf16 in/out, f32 accumulate, 8-deep MLP) ----------------
template <int FEAT>
__global__ __launch_bounds__(256)
void k_agg(const u16* __restrict__ x, const int* __restrict__ rowstart,
           const int* __restrict__ sorted_src, const float* __restrict__ epsp,
           u16* __restrict__ out) {
  int node = blockIdx.x * 4 + (threadIdx.x >> 6);
  if (node >= NN) return;
  int lane = threadIdx.x & 63;
  float e1 = 1.0f + epsp[0];
  int s = rowstart[node], t = rowstart[node + 1];
  if constexpr (FEAT == 128) {
    const u32* xp = (const u32*)x;
    u32 u = xp[(size_t)node * 64 + lane];
    float a0 = bflo(u) * e1, a1 = bfhi(u) * e1;
    int p = s;
    for (; p + 7 < t; p += 8) {
      u32 uu[8];
#pragma unroll
      for (int i = 0; i < 8; ++i) uu[i] = xp[(size_t)sorted_src[p + i] * 64 + lane];
#pragma unroll
      for (int i = 0; i < 8; ++i) { a0 += bflo(uu[i]); a1 += bfhi(uu[i]); }
    }
    for (; p < t; ++p) {
      u32 u0 = xp[(size_t)sorted_src[p] * 64 + lane];
      a0 += bflo(u0); a1 += bfhi(u0);
    }
    ((u32*)out)[(size_t)node * 64 + lane] = pack2(a0, a1);
  } else {
    const uint2* xp = (const uint2*)x;
    uint2 u = xp[(size_t)node * 64 + lane];
    float a0 = bflo(u.x) * e1, a1 = bfhi(u.x) * e1;
    float a2 = bflo(u.y) * e1, a3 = bfhi(u.y) * e1;
    int p = s;
    for (; p + 7 < t; p += 8) {
      uint2 uu[8];
#pragma unroll
      for (int i = 0; i < 8; ++i) uu[i] = xp[(size_t)sorted_src[p + i] * 64 + lane];
#pragma unroll
      for (int i = 0; i < 8; ++i) {
        a0 += bflo(uu[i].x); a1 += bfhi(uu[i].x);
        a2 += bflo(uu[i].y); a3 += bfhi(uu[i].y);
      }
    }
    for (; p < t; ++p) {
      uint2 u0 = xp[(size_t)sorted_src[p] * 64 + lane];
      a0 += bflo(u0.x); a1 += bfhi(u0.x);
      a2 += bflo(u0.y); a3 += bfhi(u0.y);
    }
    ((uint2*)out)[(size_t)node * 64 + lane] = make_uint2(pack2(a0, a1), pack2(a2, a3));
  }
}

// ---------------- BK=32 double-buffered 2-phase MFMA GEMM ----------------
// 128x256 tile, grid 391, 512 thr (8 waves 2x4, wave = 64x64). Per k-step:
// issue loads(t+1) -> MFMA(buf[t&1]) -> transform+ds_write(t+1 -> buf[t^1])
// -> ONE barrier. Global-load latency hides under the MFMA phase. 48KB LDS
// (A dbuf 16KB + B dbuf 32KB) -> 3 blocks/CU. Swizzle chunk^((row>>1)&3) -> 2-way.
template <int K, bool TRANSFORM, bool RELU_OUT, bool COLSUMS>
__global__ __launch_bounds__(512, 4)
void k_gemm(const u16* __restrict__ A, const u16* __restrict__ Wt,
            const float* __restrict__ bias,
            const float* __restrict__ icsum, const float* __restrict__ icsq,
            const float* __restrict__ g, const float* __restrict__ be,
            u16* __restrict__ C, float* __restrict__ ocsum, float* __restrict__ ocsq) {
  constexpr int NKS = K / 32;
  __shared__ u16 SMEM[2 * 128 * 32 + 2 * 256 * 32];   // A0|A1|B0|B1 = 48KB
  __shared__ float2 Tb[TRANSFORM ? 256 : 1];

  const int tid = threadIdx.x;
  const int lane = tid & 63;
  const int w = tid >> 6;
  const int wm = w >> 2, wn = w & 3;
  const int lr = lane & 15, lq = lane >> 4;
  const int r0 = blockIdx.x * 128;

  u16* const Ab0 = SMEM;
  u16* const Ab1 = SMEM + 128 * 32;
  u16* const Bb0 = SMEM + 2 * 128 * 32;
  u16* const Bb1 = SMEM + 2 * 128 * 32 + 256 * 32;

  if constexpr (TRANSFORM) {
    if (tid < 256) {
      float m = icsum[tid] * (1.0f / NN);
      float var = icsq[tid] * (1.0f / NN) - m * m;
      float s = g[tid] * rsqrtf(var + BN_EPS);
      Tb[tid] = make_float2(s, be[tid] - m * s);
    }
    __syncthreads();
  }

  // staging coordinates: A one 16B slot/thread, B two slots/thread
  const int arow = tid >> 2, ach = tid & 3;
  const int agrc = (r0 + arow) < NN ? (r0 + arow) : NN - 1;
  const int b1r = (tid + 512) >> 2;   // second B slot row (same chunk bits)

  auto WRA = [&](u16* buf, short8 v, int ks) {
    if constexpr (TRANSFORM) {
#pragma unroll
      for (int j = 0; j < 8; ++j) {
        float2 tb = Tb[ks * 32 + ach * 8 + j];
        float f = fmaxf(fmaf(__uint_as_float(((u32)(u16)v[j]) << 16), tb.x, tb.y), 0.f);
        v[j] = (short)f2bf(f);
      }
    }
    ((short8*)buf)[arow * 4 + (ach ^ ((arow >> 1) & 3))] = v;
  };
  auto WRB = [&](u16* buf, short8 v, int row) {
    ((short8*)buf)[row * 4 + (ach ^ ((row >> 1) & 3))] = v;
  };

  f32x4 acc[4][4];
#pragma unroll
  for (int mi = 0; mi < 4; ++mi)
#pragma unroll
    for (int ni = 0; ni < 4; ++ni) acc[mi][ni] = (f32x4){0.f, 0.f, 0.f, 0.f};

  // prologue: stage k-step 0 into buffer 0
  {
    short8 ra  = *(const short8*)&A[(size_t)agrc * K + ach * 8];
    short8 rb0 = *(const short8*)&Wt[(size_t)arow * K + ach * 8];
    short8 rb1 = *(const short8*)&Wt[(size_t)b1r * K + ach * 8];
    WRA(Ab0, ra, 0);
    WRB(Bb0, rb0, arow);
    WRB(Bb0, rb1, b1r);
  }
  __syncthreads();

#pragma unroll
  for (int ks = 0; ks < NKS; ++ks) {
    short8 na = (short8)0, nb0 = (short8)0, nb1 = (short8)0;
    if (ks + 1 < NKS) {               // issue next-step loads BEFORE compute
      int ko = (ks + 1) * 32 + ach * 8;
      na  = *(const short8*)&A[(size_t)agrc * K + ko];
      nb0 = *(const short8*)&Wt[(size_t)arow * K + ko];
      nb1 = *(const short8*)&Wt[(size_t)b1r * K + ko];
    }
    const u16* Ab = (ks & 1) ? Ab1 : Ab0;
    const u16* Bb = (ks & 1) ? Bb1 : Bb0;
    short8 af[4], bfx[4];
#pragma unroll
    for (int mi = 0; mi < 4; ++mi) {
      int row = wm * 64 + mi * 16 + lr;
      af[mi] = ((const short8*)Ab)[row * 4 + (lq ^ ((row >> 1) & 3))];
    }
#pragma unroll
    for (int ni = 0; ni < 4; ++ni) {
      int rn = wn * 64 + ni * 16 + lr;
      bfx[ni] = ((const short8*)Bb)[rn * 4 + (lq ^ ((rn >> 1) & 3))];
    }
#pragma unroll
    for (int mi = 0; mi < 4; ++mi)
#pragma unroll
      for (int ni = 0; ni < 4; ++ni)
        acc[mi][ni] = __builtin_amdgcn_mfma_f32_16x16x32_bf16(af[mi], bfx[ni], acc[mi][ni], 0, 0, 0);
    if (ks + 1 < NKS) {               // write next into the other buffer
      u16* An = (ks & 1) ? Ab0 : Ab1;
      u16* Bn = (ks & 1) ? Bb0 : Bb1;
      WRA(An, na, ks + 1);
      WRB(Bn, nb0, arow);
      WRB(Bn, nb1, b1r);
    }
    __syncthreads();                  // one barrier per k-step
  }

  // epilogue: bias/relu/colsums -> Cs (SMEM front, 32KB) -> 64B/thread lines
  float bv[4];
#pragma unroll
  for (int ni = 0; ni < 4; ++ni) bv[ni] = bias[wn * 64 + ni * 16 + lr];
  float colS[4] = {}, colQ[4] = {};

  u16* Cs = SMEM;
#pragma unroll
  for (int r = 0; r < 2; ++r) {
    if (wm == r) {
#pragma unroll
      for (int mi = 0; mi < 4; ++mi)
#pragma unroll
        for (int ni = 0; ni < 4; ++ni) {
          int col = wn * 64 + ni * 16 + lr;
#pragma unroll
          for (int j = 0; j < 4; ++j) {
            int lrow = mi * 16 + lq * 4 + j;
            float v = acc[mi][ni][j] + bv[ni];
            if constexpr (RELU_OUT) v = fmaxf(v, 0.f);
            if constexpr (COLSUMS) {
              if (r0 + r * 64 + lrow < NN) { colS[ni] += v; colQ[ni] += v * v; }
            }
            Cs[lrow * 256 + col] = f2bf(v);
          }
        }
    }
    __syncthreads();
    {
      int lrow = tid >> 3;
      int gr = r0 + r * 64 + lrow;
      if (gr < NN) {
        int co = (tid & 7) * 32;
#pragma unroll
        for (int i = 0; i < 4; ++i)
          *(uint4*)&C[(size_t)gr * 256 + co + i * 8] = *(const uint4*)&Cs[lrow * 256 + co + i * 8];
      }
    }
    __syncthreads();
  }

  if constexpr (COLSUMS) {
#pragma unroll
    for (int ni = 0; ni < 4; ++ni) {
      float s = colS[ni], q = colQ[ni];
      s += __shfl_xor(s, 16); s += __shfl_xor(s, 32);
      q += __shfl_xor(q, 16); q += __shfl_xor(q, 32);
      if (lq == 0) {
        int col = wn * 64 + ni * 16 + lr;
        atomicAdd(&ocsum[col], s);
        atomicAdd(&ocsq[col], q);
      }
    }
  }
}

// ---------------- final: out[N,40] = relu(bn3(z3)) @ Wf + bf ----------------
__global__ __launch_bounds__(512)
void k_final(const u16* __restrict__ z3, const u16* __restrict__ Wft,
             const float* __restrict__ bfp,
             const float* __restrict__ icsum, const float* __restrict__ icsq,
             const float* __restrict__ g, const float* __restrict__ be,
             float* __restrict__ out) {
  __shared__ u16 Bs[48 * 256];
  __shared__ float2 Tb[256];
  const int tid = threadIdx.x;
  const int lane = tid & 63;
  const int w = tid >> 6;
  const int lr = lane & 15, lq = lane >> 4;
  const int r0 = blockIdx.x * 128;

  int row = r0 + w * 16 + lr;
  int rc = row < NN ? row : NN - 1;
  const u16* Ap = &z3[(size_t)rc * 256];
  short8 a[8];
#pragma unroll
  for (int ks = 0; ks < 8; ++ks)
    a[ks] = *(const short8*)&Ap[(ks * 4 + lq) * 8];

  {
    const short8* Bv = (const short8*)Wft;
    short8* Bl = (short8*)Bs;
#pragma unroll
    for (int i = 0; i < 3; ++i)
      Bl[tid + i * 512] = Bv[tid + i * 512];
  }
  if (tid < 256) {
    float m = icsum[tid] * (1.0f / NN);
    float var = icsq[tid] * (1.0f / NN) - m * m;
    float s = g[tid] * rsqrtf(var + BN_EPS);
    Tb[tid] = make_float2(s, be[tid] - m * s);
  }
  __syncthreads();

  f32x4 acc[3];
#pragma unroll
  for (int ni = 0; ni < 3; ++ni) acc[ni] = (f32x4){0.f, 0.f, 0.f, 0.f};
#pragma unroll
  for (int ks = 0; ks < 8; ++ks) {
    short8 t0 = a[ks];
    int kb = (ks * 4 + lq) * 8;
#pragma unroll
    for (int j = 0; j < 8; ++j) {
      float2 tb = Tb[kb + j];
      float f0 = fmaxf(fmaf(__uint_as_float(((u32)(u16)t0[j]) << 16), tb.x, tb.y), 0.f);
      t0[j] = (short)f2bf(f0);
    }
#pragma unroll
    for (int ni = 0; ni < 3; ++ni) {
      int col = ni * 16 + lr;
      short8 bfr = *(const short8*)&Bs[(size_t)col * 256 + (((ks * 4 + lq) ^ (col & 7)) << 3)];
      acc[ni] = __builtin_amdgcn_mfma_f32_16x16x32_bf16(t0, bfr, acc[ni], 0, 0, 0);
    }
  }

#pragma unroll
  for (int ni = 0; ni < 3; ++ni) {
    int col = ni * 16 + lr;
    if (col < CDIM) {
      float bfv = bfp[col];
#pragma unroll
      for (int j = 0; j < 4; ++j) {
        int gr = r0 + w * 16 + lq * 4 + j;
        if (gr < NN) out[(size_t)gr * CDIM + col] = acc[ni][j] + bfv;
      }
    }
  }
}

// ---------------- launch ----------------
extern "C" void kernel_launch(void* const* d_in, const int* in_sizes, int n_in,
                              void* d_out, int out_size, void* d_ws, size_t ws_size,
                              hipStream_t stream) {
  const float* x   = (const float*)d_in[0];
  const int*   ei  = (const int*)d_in[1];
  const float* eps1= (const float*)d_in[2];
  const float* W1  = (const float*)d_in[3];
  const float* b1  = (const float*)d_in[4];
  const float* g1  = (const float*)d_in[5];
  const float* be1 = (const float*)d_in[6];
  const float* W2  = (const float*)d_in[7];
  const float* b2  = (const float*)d_in[8];
  const float* eps2= (const float*)d_in[9];
  const float* W3  = (const float*)d_in[10];
  const float* b3  = (const float*)d_in[11];
  const float* g2  = (const float*)d_in[12];
  const float* be2 = (const float*)d_in[13];
  const float* W4  = (const float*)d_in[14];
  const float* b4  = (const float*)d_in[15];
  const float* g3  = (const float*)d_in[16];
  const float* be3 = (const float*)d_in[17];
  const float* Wf  = (const float*)d_in[18];
  const float* bf  = (const float*)d_in[19];
  float* out = (float*)d_out;

  char* p = (char*)d_ws;
  auto alloc = [&](size_t bytes) -> char* {
    char* r = p;
    p += (bytes + 255) & ~(size_t)255;
    return r;
  };
  float* stats   = (float*)alloc(6 * 256 * sizeof(float));
  int* deg       = (int*)alloc(NN * sizeof(int));
  int* rowstart  = (int*)alloc((NN + 16) * sizeof(int));
  int* cursor    = (int*)alloc(NN * sizeof(int));
  int* sorted    = (int*)alloc(EE * sizeof(int));
  int* partial   = (int*)alloc(NN * sizeof(int));
  int* bsums     = (int*)alloc(1024 * sizeof(int));
  u16* W1t       = (u16*)alloc(256 * 128 * sizeof(u16));
  u16* W2t       = (u16*)alloc(256 * 256 * sizeof(u16));
  u16* W3t       = (u16*)alloc(256 * 256 * sizeof(u16));
  u16* W4t       = (u16*)alloc(256 * 256 * sizeof(u16));
  u16* Wft       = (u16*)alloc(48 * 256 * sizeof(u16));
  u16* xb        = (u16*)alloc((size_t)NN * 128 * sizeof(u16));
  u16* A1        = (u16*)alloc((size_t)NN * 128 * sizeof(u16));
  u16* z1        = (u16*)alloc((size_t)NN * 256 * sizeof(u16));
  u16* h1        = (u16*)alloc((size_t)NN * 256 * sizeof(u16));
  u16* A2        = (u16*)alloc((size_t)NN * 256 * sizeof(u16));
  (void)alloc(64 * 1024);  // guard pad
  u16* z2 = z1;
  u16* z3 = h1;

  float* s1 = stats + 0,    *q1 = stats + 256;
  float* s2 = stats + 512,  *q2 = stats + 768;
  float* s3 = stats + 1024, *q3 = stats + 1280;

  const int nbN = (NN + 255) / 256;

  hipMemsetAsync(stats, 0, 6 * 256 * sizeof(float) + NN * sizeof(int), stream);

  k_pre<<<NB_CVTX + NB_CVTW + NB_HIST, 256, 0, stream>>>(
      x, xb, ei, deg, W1, W2, W3, W4, Wf, W1t, W2t, W3t, W4t, Wft);
  k_scan_blocks<<<nbN, 256, 0, stream>>>(deg, partial, bsums, NN);
  k_scan_sums<<<1, 256, 0, stream>>>(bsums, nbN);
  k_scan_add<<<nbN, 256, 0, stream>>>(partial, bsums, deg, rowstart, cursor, NN);
  k_scatter<<<SC_NCHUNK * SC_NWIN, 256, 0, stream>>>(ei, cursor, sorted);

  const int gGemm = (NN + 127) / 128;   // 391

  // conv1
  k_agg<128><<<(NN + 3) / 4, 256, 0, stream>>>(xb, rowstart, sorted, eps1, A1);
  k_gemm<128, false, false, true><<<gGemm, 512, 0, stream>>>(
      A1, W1t, b1, nullptr, nullptr, nullptr, nullptr, z1, s1, q1);
  k_gemm<256, true, true, false><<<gGemm, 512, 0, stream>>>(
      z1, W2t, b2, s1, q1, g1, be1, h1, nullptr, nullptr);

  // conv2
  k_agg<256><<<(NN + 3) / 4, 256, 0, stream>>>(h1, rowstart, sorted, eps2, A2);
  k_gemm<256, false, false, true><<<gGemm, 512, 0, stream>>>(
      A2, W3t, b3, nullptr, nullptr, nullptr, nullptr, z2, s2, q2);
  k_gemm<256, true, false, true><<<gGemm, 512, 0, stream>>>(
      z2, W4t, b4, s2, q2, g2, be2, z3, s3, q3);

  // final
  k_final<<<(NN + 127) / 128, 512, 0, stream>>>(z3, Wft, bf, s3, q3, g3, be3, out);
}

// Round 21
// 321.088 us; speedup vs baseline: 1.0416x; 1.0099x over previous
//
#include <hip/hip_runtime.h>
#include <hip/hip_bf16.h>

// GIN forward, MI355X. R21 = R20 + s_setprio(1) around the GEMM MFMA cluster
// (T5: now valid — the 2-phase dbuf schedule has wave-role diversity).

#define NN 50000
#define EE 800000
#define FDIM 128
#define HDIM 256
#define CDIM 40
#define BN_EPS 1e-5f

typedef unsigned short u16;
typedef unsigned int u32;
typedef __attribute__((ext_vector_type(8))) short short8;
typedef __attribute__((ext_vector_type(4))) float f32x4;

__device__ __forceinline__ float bflo(u32 u) { return __uint_as_float(u << 16); }
__device__ __forceinline__ float bfhi(u32 u) { return __uint_as_float(u & 0xFFFF0000u); }
__device__ __forceinline__ u16 f2bf(float f) {
  __hip_bfloat16 h = __float2bfloat16(f);
  return *(u16*)&h;
}
__device__ __forceinline__ u32 pack2(float a, float b) {
  return (u32)f2bf(a) | ((u32)f2bf(b) << 16);
}

// ---------------- CSR build ----------------
__global__ void k_scan_blocks(const int* __restrict__ in, int* __restrict__ partial,
                              int* __restrict__ bsums, int n) {
  __shared__ int s[256];
  int i = blockIdx.x * 256 + threadIdx.x;
  s[threadIdx.x] = (i < n) ? in[i] : 0;
  __syncthreads();
  for (int d = 1; d < 256; d <<= 1) {
    int t = (threadIdx.x >= d) ? s[threadIdx.x - d] : 0;
    __syncthreads();
    s[threadIdx.x] += t;
    __syncthreads();
  }
  if (i < n) partial[i] = s[threadIdx.x];
  if (threadIdx.x == 255) bsums[blockIdx.x] = s[255];
}

__global__ void k_scan_sums(int* __restrict__ bs, int nb) {
  __shared__ int s[256];
  s[threadIdx.x] = (threadIdx.x < nb) ? bs[threadIdx.x] : 0;
  __syncthreads();
  for (int d = 1; d < 256; d <<= 1) {
    int t = (threadIdx.x >= d) ? s[threadIdx.x - d] : 0;
    __syncthreads();
    s[threadIdx.x] += t;
    __syncthreads();
  }
  int ex = (threadIdx.x == 0) ? 0 : s[threadIdx.x - 1];
  if (threadIdx.x < nb) bs[threadIdx.x] = ex;
}

__global__ void k_scan_add(const int* __restrict__ partial, const int* __restrict__ bs,
                           const int* __restrict__ deg,
                           int* __restrict__ rowstart, int* __restrict__ cursor, int n) {
  int i = blockIdx.x * 256 + threadIdx.x;
  if (i < n) {
    int incl = partial[i] + bs[blockIdx.x];
    rowstart[i + 1] = incl;
    cursor[i] = incl - deg[i];
  }
  if (i == 0) rowstart[0] = 0;
}

// XCD-spatial scatter (window = bid&7): proven -9us in R16 (plain-store locality).
#define SC_CHUNK 1024
#define SC_NCHUNK ((EE + SC_CHUNK - 1) / SC_CHUNK)   // 782
#define SC_NWIN 8
#define SC_WINSZ 6250
__global__ __launch_bounds__(256)
void k_scatter(const int* __restrict__ ei, int* __restrict__ cursor,
               int* __restrict__ sorted_src) {
  int win = blockIdx.x & (SC_NWIN - 1);
  int chunk = blockIdx.x >> 3;
  int wlo = win * SC_WINSZ, whi = wlo + SC_WINSZ;
  int e0 = chunk * SC_CHUNK + threadIdx.x * 4;
  if (e0 >= EE) return;
  int4 s4 = *(const int4*)&ei[e0];
  int4 d4 = *(const int4*)&ei[EE + e0];
  int ss[4] = {s4.x, s4.y, s4.z, s4.w};
  int dd[4] = {d4.x, d4.y, d4.z, d4.w};
#pragma unroll
  for (int i = 0; i < 4; ++i) {
    if (dd[i] >= wlo && dd[i] < whi) {
      int p = atomicAdd(&cursor[dd[i]], 1);
      sorted_src[p] = ss[i];
    }
  }
}

// ---------------- fused prework: cvt_x | cvt_w (plain transpose) | hist ----------------
#define NB_CVTX 6250
#define NB_CVTW 944
#define NB_HIST 3125
__global__ void k_pre(const float* __restrict__ x, u16* __restrict__ xb,
                      const int* __restrict__ ei, int* __restrict__ deg,
                      const float* __restrict__ W1, const float* __restrict__ W2,
                      const float* __restrict__ W3, const float* __restrict__ W4,
                      const float* __restrict__ Wf,
                      u16* __restrict__ W1t, u16* __restrict__ W2t,
                      u16* __restrict__ W3t, u16* __restrict__ W4t,
                      u16* __restrict__ Wft) {
  int b = blockIdx.x, t = threadIdx.x;
  if (b < NB_CVTX) {
    size_t base = ((size_t)b * 256 + t) * 4;
    float4 v = *(const float4*)&x[base];
    *(uint2*)&xb[base] = make_uint2(pack2(v.x, v.y), pack2(v.z, v.w));
  } else if (b < NB_CVTX + NB_CVTW) {
    int bb = b - NB_CVTX;
    if (bb < 128) {
      int i = bb * 256 + t; int k = i >> 8, n = i & 255;
      W1t[(size_t)n * 128 + k] = f2bf(W1[i]);
    } else if (bb < 384) {
      int i = (bb - 128) * 256 + t; int k = i >> 8, n = i & 255;
      W2t[(size_t)n * 256 + k] = f2bf(W2[i]);
    } else if (bb < 640) {
      int i = (bb - 384) * 256 + t; int k = i >> 8, n = i & 255;
      W3t[(size_t)n * 256 + k] = f2bf(W3[i]);
    } else if (bb < 896) {
      int i = (bb - 640) * 256 + t; int k = i >> 8, n = i & 255;
      W4t[(size_t)n * 256 + k] = f2bf(W4[i]);
    } else {
      int j = (bb - 896) * 256 + t;
      int c = j >> 8, k = j & 255;
      float v = (c < CDIM) ? Wf[(size_t)k * CDIM + c] : 0.f;
      Wft[(size_t)c * 256 + (((k >> 3) ^ (c & 7)) << 3) + (k & 7)] = f2bf(v);
    }
  } else {
    int e = (b - NB_CVTX - NB_CVTW) * 256 + t;
    atomicAdd(&deg[ei[EE + e]], 1);
  }
}

// ---------------- aggregation (bf16 in/out, f32 accumulate, 8-deep MLP) ----------------
template <int FEAT>
__global__ __launch_bounds__(256)
void k_agg(const u16* __restrict__ x, const int* __restrict__ rowstart,
           const int* __restrict__ sorted_src, const float* __restrict__ epsp,
           u16* __restrict__ out) {
  int node = blockIdx.x * 4 + (threadIdx.x >> 6);
  if (node >= NN) return;
  int lane = threadIdx.x & 63;
  float e1 = 1.0f + epsp[0];
  int s = rowstart[node], t = rowstart[node + 1];
  if constexpr (FEAT == 128) {
    const u32* xp = (const u32*)x;
    u32 u = xp[(size_t)node * 64 + lane];
    float a0 = bflo(u) * e1, a1 = bfhi(u) * e1;
    int p = s;
    for (; p + 7 < t; p += 8) {
      u32 uu[8];
#pragma unroll
      for (int i = 0; i < 8; ++i) uu[i] = xp[(size_t)sorted_src[p + i] * 64 + lane];
#pragma unroll
      for (int i = 0; i < 8; ++i) { a0 += bflo(uu[i]); a1 += bfhi(uu[i]); }
    }
    for (; p < t; ++p) {
      u32 u0 = xp[(size_t)sorted_src[p] * 64 + lane];
      a0 += bflo(u0); a1 += bfhi(u0);
    }
    ((u32*)out)[(size_t)node * 64 + lane] = pack2(a0, a1);
  } else {
    const uint2* xp = (const uint2*)x;
    uint2 u = xp[(size_t)node * 64 + lane];
    float a0 = bflo(u.x) * e1, a1 = bfhi(u.x) * e1;
    float a2 = bflo(u.y) * e1, a3 = bfhi(u.y) * e1;
    int p = s;
    for (; p + 7 < t; p += 8) {
      uint2 uu[8];
#pragma unroll
      for (int i = 0; i < 8; ++i) uu[i] = xp[(size_t)sorted_src[p + i] * 64 + lane];
#pragma unroll
      for (int i = 0; i < 8; ++i) {
        a0 += bflo(uu[i].x); a1 += bfhi(uu[i].x);
        a2 += bflo(uu[i].y); a3 += bfhi(uu[i].y);
      }
    }
    for (; p < t; ++p) {
      uint2 u0 = xp[(size_t)sorted_src[p] * 64 + lane];
      a0 += bflo(u0.x); a1 += bfhi(u0.x);
      a2 += bflo(u0.y); a3 += bfhi(u0.y);
    }
    ((uint2*)out)[(size_t)node * 64 + lane] = make_uint2(pack2(a0, a1), pack2(a2, a3));
  }
}

// ---------------- BK=32 double-buffered 2-phase MFMA GEMM (+T5 setprio) ----------------
template <int K, bool TRANSFORM, bool RELU_OUT, bool COLSUMS>
__global__ __launch_bounds__(512, 4)
void k_gemm(const u16* __restrict__ A, const u16* __restrict__ Wt,
            const float* __restrict__ bias,
            const float* __restrict__ icsum, const float* __restrict__ icsq,
            const float* __restrict__ g, const float* __restrict__ be,
            u16* __restrict__ C, float* __restrict__ ocsum, float* __restrict__ ocsq) {
  constexpr int NKS = K / 32;
  __shared__ u16 SMEM[2 * 128 * 32 + 2 * 256 * 32];   // A0|A1|B0|B1 = 48KB
  __shared__ float2 Tb[TRANSFORM ? 256 : 1];

  const int tid = threadIdx.x;
  const int lane = tid & 63;
  const int w = tid >> 6;
  const int wm = w >> 2, wn = w & 3;
  const int lr = lane & 15, lq = lane >> 4;
  const int r0 = blockIdx.x * 128;

  u16* const Ab0 = SMEM;
  u16* const Ab1 = SMEM + 128 * 32;
  u16* const Bb0 = SMEM + 2 * 128 * 32;
  u16* const Bb1 = SMEM + 2 * 128 * 32 + 256 * 32;

  if constexpr (TRANSFORM) {
    if (tid < 256) {
      float m = icsum[tid] * (1.0f / NN);
      float var = icsq[tid] * (1.0f / NN) - m * m;
      float s = g[tid] * rsqrtf(var + BN_EPS);
      Tb[tid] = make_float2(s, be[tid] - m * s);
    }
    __syncthreads();
  }

  const int arow = tid >> 2, ach = tid & 3;
  const int agrc = (r0 + arow) < NN ? (r0 + arow) : NN - 1;
  const int b1r = (tid + 512) >> 2;

  auto WRA = [&](u16* buf, short8 v, int ks) {
    if constexpr (TRANSFORM) {
#pragma unroll
      for (int j = 0; j < 8; ++j) {
        float2 tb = Tb[ks * 32 + ach * 8 + j];
        float f = fmaxf(fmaf(__uint_as_float(((u32)(u16)v[j]) << 16), tb.x, tb.y), 0.f);
        v[j] = (short)f2bf(f);
      }
    }
    ((short8*)buf)[arow * 4 + (ach ^ ((arow >> 1) & 3))] = v;
  };
  auto WRB = [&](u16* buf, short8 v, int row) {
    ((short8*)buf)[row * 4 + (ach ^ ((row >> 1) & 3))] = v;
  };

  f32x4 acc[4][4];
#pragma unroll
  for (int mi = 0; mi < 4; ++mi)
#pragma unroll
    for (int ni = 0; ni < 4; ++ni) acc[mi][ni] = (f32x4){0.f, 0.f, 0.f, 0.f};

  {
    short8 ra  = *(const short8*)&A[(size_t)agrc * K + ach * 8];
    short8 rb0 = *(const short8*)&Wt[(size_t)arow * K + ach * 8];
    short8 rb1 = *(const short8*)&Wt[(size_t)b1r * K + ach * 8];
    WRA(Ab0, ra, 0);
    WRB(Bb0, rb0, arow);
    WRB(Bb0, rb1, b1r);
  }
  __syncthreads();

#pragma unroll
  for (int ks = 0; ks < NKS; ++ks) {
    short8 na = (short8)0, nb0 = (short8)0, nb1 = (short8)0;
    if (ks + 1 < NKS) {
      int ko = (ks + 1) * 32 + ach * 8;
      na  = *(const short8*)&A[(size_t)agrc * K + ko];
      nb0 = *(const short8*)&Wt[(size_t)arow * K + ko];
      nb1 = *(const short8*)&Wt[(size_t)b1r * K + ko];
    }
    const u16* Ab = (ks & 1) ? Ab1 : Ab0;
    const u16* Bb = (ks & 1) ? Bb1 : Bb0;
    short8 af[4], bfx[4];
#pragma unroll
    for (int mi = 0; mi < 4; ++mi) {
      int row = wm * 64 + mi * 16 + lr;
      af[mi] = ((const short8*)Ab)[row * 4 + (lq ^ ((row >> 1) & 3))];
    }
#pragma unroll
    for (int ni = 0; ni < 4; ++ni) {
      int rn = wn * 64 + ni * 16 + lr;
      bfx[ni] = ((const short8*)Bb)[rn * 4 + (lq ^ ((rn >> 1) & 3))];
    }
    __builtin_amdgcn_s_setprio(1);            // T5: favor MFMA-entering waves
#pragma unroll
    for (int mi = 0; mi < 4; ++mi)
#pragma unroll
      for (int ni = 0; ni < 4; ++ni)
        acc[mi][ni] = __builtin_amdgcn_mfma_f32_16x16x32_bf16(af[mi], bfx[ni], acc[mi][ni], 0, 0, 0);
    __builtin_amdgcn_s_setprio(0);
    if (ks + 1 < NKS) {
      u16* An = (ks & 1) ? Ab0 : Ab1;
      u16* Bn = (ks & 1) ? Bb0 : Bb1;
      WRA(An, na, ks + 1);
      WRB(Bn, nb0, arow);
      WRB(Bn, nb1, b1r);
    }
    __syncthreads();
  }

  float bv[4];
#pragma unroll
  for (int ni = 0; ni < 4; ++ni) bv[ni] = bias[wn * 64 + ni * 16 + lr];
  float colS[4] = {}, colQ[4] = {};

  u16* Cs = SMEM;
#pragma unroll
  for (int r = 0; r < 2; ++r) {
    if (wm == r) {
#pragma unroll
      for (int mi = 0; mi < 4; ++mi)
#pragma unroll
        for (int ni = 0; ni < 4; ++ni) {
          int col = wn * 64 + ni * 16 + lr;
#pragma unroll
          for (int j = 0; j < 4; ++j) {
            int lrow = mi * 16 + lq * 4 + j;
            float v = acc[mi][ni][j] + bv[ni];
            if constexpr (RELU_OUT) v = fmaxf(v, 0.f);
            if constexpr (COLSUMS) {
              if (r0 + r * 64 + lrow < NN) { colS[ni] += v; colQ[ni] += v * v; }
            }
            Cs[lrow * 256 + col] = f2bf(v);
          }
        }
    }
    __syncthreads();
    {
      int lrow = tid >> 3;
      int gr = r0 + r * 64 + lrow;
      if (gr < NN) {
        int co = (tid & 7) * 32;
#pragma unroll
        for (int i = 0; i < 4; ++i)
          *(uint4*)&C[(size_t)gr * 256 + co + i * 8] = *(const uint4*)&Cs[lrow * 256 + co + i * 8];
      }
    }
    __syncthreads();
  }

  if constexpr (COLSUMS) {
#pragma unroll
    for (int ni = 0; ni < 4; ++ni) {
      float s = colS[ni], q = colQ[ni];
      s += __shfl_xor(s, 16); s += __shfl_xor(s, 32);
      q += __shfl_xor(q, 16); q += __shfl_xor(q, 32);
      if (lq == 0) {
        int col = wn * 64 + ni * 16 + lr;
        atomicAdd(&ocsum[col], s);
        atomicAdd(&ocsq[col], q);
      }
    }
  }
}

// ---------------- final: out[N,40] = relu(bn3(z3)) @ Wf + bf ----------------
__global__ __launch_bounds__(512)
void k_final(const u16* __restrict__ z3, const u16* __restrict__ Wft,
             const float* __restrict__ bfp,
             const float* __restrict__ icsum, const float* __restrict__ icsq,
             const float* __restrict__ g, const float* __restrict__ be,
             float* __restrict__ out) {
  __shared__ u16 Bs[48 * 256];
  __shared__ float2 Tb[256];
  const int tid = threadIdx.x;
  const int lane = tid & 63;
  const int w = tid >> 6;
  const int lr = lane & 15, lq = lane >> 4;
  const int r0 = blockIdx.x * 128;

  int row = r0 + w * 16 + lr;
  int rc = row < NN ? row : NN - 1;
  const u16* Ap = &z3[(size_t)rc * 256];
  short8 a[8];
#pragma unroll
  for (int ks = 0; ks < 8; ++ks)
    a[ks] = *(const short8*)&Ap[(ks * 4 + lq) * 8];

  {
    const short8* Bv = (const short8*)Wft;
    short8* Bl = (short8*)Bs;
#pragma unroll
    for (int i = 0; i < 3; ++i)
      Bl[tid + i * 512] = Bv[tid + i * 512];
  }
  if (tid < 256) {
    float m = icsum[tid] * (1.0f / NN);
    float var = icsq[tid] * (1.0f / NN) - m * m;
    float s = g[tid] * rsqrtf(var + BN_EPS);
    Tb[tid] = make_float2(s, be[tid] - m * s);
  }
  __syncthreads();

  f32x4 acc[3];
#pragma unroll
  for (int ni = 0; ni < 3; ++ni) acc[ni] = (f32x4){0.f, 0.f, 0.f, 0.f};
#pragma unroll
  for (int ks = 0; ks < 8; ++ks) {
    short8 t0 = a[ks];
    int kb = (ks * 4 + lq) * 8;
#pragma unroll
    for (int j = 0; j < 8; ++j) {
      float2 tb = Tb[kb + j];
      float f0 = fmaxf(fmaf(__uint_as_float(((u32)(u16)t0[j]) << 16), tb.x, tb.y), 0.f);
      t0[j] = (short)f2bf(f0);
    }
#pragma unroll
    for (int ni = 0; ni < 3; ++ni) {
      int col = ni * 16 + lr;
      short8 bfr = *(const short8*)&Bs[(size_t)col * 256 + (((ks * 4 + lq) ^ (col & 7)) << 3)];
      acc[ni] = __builtin_amdgcn_mfma_f32_16x16x32_bf16(t0, bfr, acc[ni], 0, 0, 0);
    }
  }

#pragma unroll
  for (int ni = 0; ni < 3; ++ni) {
    int col = ni * 16 + lr;
    if (col < CDIM) {
      float bfv = bfp[col];
#pragma unroll
      for (int j = 0; j < 4; ++j) {
        int gr = r0 + w * 16 + lq * 4 + j;
        if (gr < NN) out[(size_t)gr * CDIM + col] = acc[ni][j] + bfv;
      }
    }
  }
}

// ---------------- launch ----------------
extern "C" void kernel_launch(void* const* d_in, const int* in_sizes, int n_in,
                              void* d_out, int out_size, void* d_ws, size_t ws_size,
                              hipStream_t stream) {
  const float* x   = (const float*)d_in[0];
  const int*   ei  = (const int*)d_in[1];
  const float* eps1= (const float*)d_in[2];
  const float* W1  = (const float*)d_in[3];
  const float* b1  = (const float*)d_in[4];
  const float* g1  = (const float*)d_in[5];
  const float* be1 = (const float*)d_in[6];
  const float* W2  = (const float*)d_in[7];
  const float* b2  = (const float*)d_in[8];
  const float* eps2= (const float*)d_in[9];
  const float* W3  = (const float*)d_in[10];
  const float* b3  = (const float*)d_in[11];
  const float* g2  = (const float*)d_in[12];
  const float* be2 = (const float*)d_in[13];
  const float* W4  = (const float*)d_in[14];
  const float* b4  = (const float*)d_in[15];
  const float* g3  = (const float*)d_in[16];
  const float* be3 = (const float*)d_in[17];
  const float* Wf  = (const float*)d_in[18];
  const float* bf  = (const float*)d_in[19];
  float* out = (float*)d_out;

  char* p = (char*)d_ws;
  auto alloc = [&](size_t bytes) -> char* {
    char* r = p;
    p += (bytes + 255) & ~(size_t)255;
    return r;
  };
  float* stats   = (float*)alloc(6 * 256 * sizeof(float));
  int* deg       = (int*)alloc(NN * sizeof(int));
  int* rowstart  = (int*)alloc((NN + 16) * sizeof(int));
  int* cursor    = (int*)alloc(NN * sizeof(int));
  int* sorted    = (int*)alloc(EE * sizeof(int));
  int* partial   = (int*)alloc(NN * sizeof(int));
  int* bsums     = (int*)alloc(1024 * sizeof(int));
  u16* W1t       = (u16*)alloc(256 * 128 * sizeof(u16));
  u16* W2t       = (u16*)alloc(256 * 256 * sizeof(u16));
  u16* W3t       = (u16*)alloc(256 * 256 * sizeof(u16));
  u16* W4t       = (u16*)alloc(256 * 256 * sizeof(u16));
  u16* Wft       = (u16*)alloc(48 * 256 * sizeof(u16));
  u16* xb        = (u16*)alloc((size_t)NN * 128 * sizeof(u16));
  u16* A1        = (u16*)alloc((size_t)NN * 128 * sizeof(u16));
  u16* z1        = (u16*)alloc((size_t)NN * 256 * sizeof(u16));
  u16* h1        = (u16*)alloc((size_t)NN * 256 * sizeof(u16));
  u16* A2        = (u16*)alloc((size_t)NN * 256 * sizeof(u16));
  (void)alloc(64 * 1024);  // guard pad
  u16* z2 = z1;
  u16* z3 = h1;

  float* s1 = stats + 0,    *q1 = stats + 256;
  float* s2 = stats + 512,  *q2 = stats + 768;
  float* s3 = stats + 1024, *q3 = stats + 1280;

  const int nbN = (NN + 255) / 256;

  hipMemsetAsync(stats, 0, 6 * 256 * sizeof(float) + NN * sizeof(int), stream);

  k_pre<<<NB_CVTX + NB_CVTW + NB_HIST, 256, 0, stream>>>(
      x, xb, ei, deg, W1, W2, W3, W4, Wf, W1t, W2t, W3t, W4t, Wft);
  k_scan_blocks<<<nbN, 256, 0, stream>>>(deg, partial, bsums, NN);
  k_scan_sums<<<1, 256, 0, stream>>>(bsums, nbN);
  k_scan_add<<<nbN, 256, 0, stream>>>(partial, bsums, deg, rowstart, cursor, NN);
  k_scatter<<<SC_NCHUNK * SC_NWIN, 256, 0, stream>>>(ei, cursor, sorted);

  const int gGemm = (NN + 127) / 128;   // 391

  // conv1
  k_agg<128><<<(NN + 3) / 4, 256, 0, stream>>>(xb, rowstart, sorted, eps1, A1);
  k_gemm<128, false, false, true><<<gGemm, 512, 0, stream>>>(
      A1, W1t, b1, nullptr, nullptr, nullptr, nullptr, z1, s1, q1);
  k_gemm<256, true, true, false><<<gGemm, 512, 0, stream>>>(
      z1, W2t, b2, s1, q1, g1, be1, h1, nullptr, nullptr);

  // conv2
  k_agg<256><<<(NN + 3) / 4, 256, 0, stream>>>(h1, rowstart, sorted, eps2, A2);
  k_gemm<256, false, false, true><<<gGemm, 512, 0, stream>>>(
      A2, W3t, b3, nullptr, nullptr, nullptr, nullptr, z2, s2, q2);
  k_gemm<256, true, false, true><<<gGemm, 512, 0, stream>>>(
      z2, W4t, b4, s2, q2, g2, be2, z3, s3, q3);

  // final
  k_final<<<(NN + 127) / 128, 512, 0, stream>>>(z3, Wft, bf, s3, q3, g3, be3, out);
}